// Round 12
// baseline (318.631 us; speedup 1.0000x reference)
//
#include <hip/hip_runtime.h>
#include <hip/hip_bf16.h>

// ---------------- problem constants ----------------
#define B_TOTAL   32768
#define L_SITES   256
#define N_MID     254        // L-2 middle sites
#define HALF_PI_F 1.57079632679489662f
#define EPS_NORM  1e-8f

// ---------------- ws layout (float/dword slots) ----------------
// Common:
// [WS_FRAG .. +520191]  B-fragment table: 254 steps x 8 frags x 64 lanes x 4 dwords
// [WS_C0   .. +63]      core0 fp32  [f][32]
// [WS_CN   .. +639]     coreN fp32  [f][a][10]
// Fallback path (round-11 verbatim, ws >= 35.6 MB):
// [WS_X    .. +8388607] xT fp32 [L][B]          [WS_FLAG] u32 dtype flag
// SC path (ws >= 69.2 MB):
// [WS_SC   .. +16777215 float2s as floats] (cos,sin) pairs [L][B]   [WS_FLAG2]
#define WS_FRAG  0
#define WS_C0    520192
#define WS_CN    520256
#define WS_X     520896
#define WS_FLAG  8909504
#define WS_SC    520896
#define WS_FLAG2 17298112
#define WS_NEEDED_SC ((size_t)(WS_FLAG2 + 1) * 4)

typedef short bf16x8 __attribute__((ext_vector_type(8)));
typedef float f32x4  __attribute__((ext_vector_type(4)));

__device__ __forceinline__ unsigned short f2bf(float f) {
    unsigned u = __builtin_bit_cast(unsigned, f);
    u += 0x7FFFu + ((u >> 16) & 1u);          // RNE
    return (unsigned short)(u >> 16);
}
__device__ __forceinline__ float bf2f(unsigned short h) {
    unsigned u = ((unsigned)h) << 16;
    return __builtin_bit_cast(float, u);
}
__device__ __forceinline__ bf16x8 asbf(uint4 u) {
    return __builtin_bit_cast(bf16x8, u);
}
// packed RNE f32x2 -> bf16x2 (v_cvt_pk_bf16_f32); bit-identical to scalar f2bf
__device__ __forceinline__ unsigned pkbf2(float a, float b) {
    float2 p; p.x = a; p.y = b;
    __hip_bfloat162 h2 = __float22bfloat162_rn(p);
    unsigned u;
    __builtin_memcpy(&u, &h2, 4);
    return u;
}
// split 8 fp32 into hi/lo bf16 fragments via packed cvt (round-8/11 proven)
__device__ __forceinline__ void split8(const float* v, bf16x8& hi, bf16x8& lo) {
    uint4 H, L;
    unsigned* hp = (unsigned*)&H;
    unsigned* lp = (unsigned*)&L;
    #pragma unroll
    for (int d = 0; d < 4; ++d) {
        float a = v[2 * d], b = v[2 * d + 1];
        unsigned hb = pkbf2(a, b);
        float h0 = __builtin_bit_cast(float, hb << 16);
        float h1 = __builtin_bit_cast(float, hb & 0xFFFF0000u);
        hp[d] = hb;
        lp[d] = pkbf2(a - h0, b - h1);
    }
    hi = __builtin_bit_cast(bf16x8, H);
    lo = __builtin_bit_cast(bf16x8, L);
}
__device__ __forceinline__ bool detect_bf16(const unsigned* x_raw, int lane) {
    unsigned v = x_raw[lane];
    return __ballot((v & 0xFFFFu) >= 0x4000u) == 0ull;
}

// ================= shared aux body pieces =================
__device__ __forceinline__ void frag_build_body(int i, bool bf,
                                                const void* am_in, float* ws) {
    if (i < N_MID * 8 * 64) {
        const int l  = i & 63;
        const int q  = (i >> 6) & 7;
        const int t  = i >> 9;
        const int h  = q >> 2;
        const int kh = (q >> 1) & 1;
        const int p  = q & 1;
        const int n  = h * 16 + (l & 15);
        const int kb = (l >> 4) * 8;
        unsigned dw[4];
        #pragma unroll
        for (int d = 0; d < 4; ++d) {
            unsigned e01[2];
            #pragma unroll
            for (int s = 0; s < 2; ++s) {
                int a = kb + 2 * d + s;
                size_t idx = ((size_t)(t * 2 + kh) * 32 + a) * 32 + n;
                float v = bf ? bf2f(((const unsigned short*)am_in)[idx])
                             : ((const float*)am_in)[idx];
                unsigned short hi = f2bf(v);
                e01[s] = (p == 0) ? hi : f2bf(v - bf2f(hi));
            }
            dw[d] = e01[0] | (e01[1] << 16);
        }
        uint4 o; o.x = dw[0]; o.y = dw[1]; o.z = dw[2]; o.w = dw[3];
        ((uint4*)ws)[(size_t)(t * 8 + q) * 64 + l] = o;
    }
}
__device__ __forceinline__ void small_body(bool bf, const void* c0_in,
                                           const void* cn_in, float* ws) {
    for (int i = threadIdx.x; i < 640; i += 256) {
        if (i < 64)
            ws[WS_C0 + i] = bf ? bf2f(((const unsigned short*)c0_in)[i])
                               : ((const float*)c0_in)[i];
        ws[WS_CN + i] = bf ? bf2f(((const unsigned short*)cn_in)[i])
                           : ((const float*)cn_in)[i];
    }
}

// ---------------- fallback aux kernel (round-11 verbatim behavior) ----------------
__global__ __launch_bounds__(256)
void aux_all(const void* __restrict__ x_in, const void* __restrict__ c0_in,
             const void* __restrict__ am_in, const void* __restrict__ cn_in,
             float* __restrict__ ws) {
    const int lane = threadIdx.x & 63;
    const bool bf = detect_bf16((const unsigned*)x_in, lane);
    const int b = blockIdx.x;
    if (b < 2048) {
        __shared__ float tile[64][65];
        const int bb = (b & 511) * 64;
        const int ll = (b >> 9) * 64;
        #pragma unroll
        for (int k = 0; k < 16; ++k) {
            int idx = threadIdx.x + k * 256;
            int row = idx >> 6, col = idx & 63;
            size_t gi = (size_t)(bb + row) * L_SITES + ll + col;
            float v = bf ? bf2f(((const unsigned short*)x_in)[gi])
                         : ((const float*)x_in)[gi];
            tile[row][col] = v;
        }
        __syncthreads();
        #pragma unroll
        for (int k = 0; k < 16; ++k) {
            int idx = threadIdx.x + k * 256;
            int row = idx >> 6, col = idx & 63;
            ws[WS_X + (size_t)(ll + row) * B_TOTAL + bb + col] = tile[col][row];
        }
    } else if (b < 2556) {
        frag_build_body((b - 2048) * 256 + threadIdx.x, bf, am_in, ws);
    } else {
        small_body(bf, c0_in, cn_in, ws);
        if (threadIdx.x == 0) *(unsigned*)(ws + WS_FLAG) = bf ? 1u : 0u;
    }
}

// ---------------- SC aux kernel: sincos table instead of xT ----------------
// Identical structure; transpose blocks emit (cos, sin) float2 computed by the
// SAME __sincosf on the SAME values -> chain bits unchanged.
__global__ __launch_bounds__(256)
void aux_sc(const void* __restrict__ x_in, const void* __restrict__ c0_in,
            const void* __restrict__ am_in, const void* __restrict__ cn_in,
            float* __restrict__ ws) {
    const int lane = threadIdx.x & 63;
    const bool bf = detect_bf16((const unsigned*)x_in, lane);
    const int b = blockIdx.x;
    if (b < 2048) {
        __shared__ float tile[64][65];
        const int bb = (b & 511) * 64;
        const int ll = (b >> 9) * 64;
        #pragma unroll
        for (int k = 0; k < 16; ++k) {
            int idx = threadIdx.x + k * 256;
            int row = idx >> 6, col = idx & 63;
            size_t gi = (size_t)(bb + row) * L_SITES + ll + col;
            float v = bf ? bf2f(((const unsigned short*)x_in)[gi])
                         : ((const float*)x_in)[gi];
            tile[row][col] = v;
        }
        __syncthreads();
        float2* SC = (float2*)(ws + WS_SC);
        #pragma unroll
        for (int k = 0; k < 16; ++k) {
            int idx = threadIdx.x + k * 256;
            int row = idx >> 6, col = idx & 63;
            float v = tile[col][row];
            float sn, cs; __sincosf(HALF_PI_F * v, &sn, &cs);
            float2 p; p.x = cs; p.y = sn;
            SC[(size_t)(ll + row) * B_TOTAL + bb + col] = p;
        }
    } else if (b < 2556) {
        frag_build_body((b - 2048) * 256 + threadIdx.x, bf, am_in, ws);
    } else {
        small_body(bf, c0_in, cn_in, ws);
        if (threadIdx.x == 0) *(unsigned*)(ws + WS_FLAG2) = bf ? 1u : 0u;
    }
}

// ================= main chain kernels =================
// Both compute EXACTLY round-7's chain bits (proven absmax 4.88e-3):
// two scaled splits, 4x 3-MFMA chains + pairwise adds, stride-33 LDS
// transpose, per-step normalization. mps_sc replaces in-loop sincos with
// prefetched (cos,sin) pairs from the aux table — pure scheduling change.

#define CHAIN_STEP_BODY(CT, ST)                                                          \
    {                                                                                    \
        float s0[8], s1[8];                                                              \
        _Pragma("unroll")                                                                \
        for (int j = 0; j < 8; ++j) { s0[j] = (CT) * mm[j]; s1[j] = (ST) * mm[j]; }      \
        bf16x8 m0h, m0l, m1h, m1l;                                                       \
        split8(s0, m0h, m0l);                                                            \
        split8(s1, m1h, m1l);                                                            \
        const f32x4 z = {0.f, 0.f, 0.f, 0.f};                                            \
        f32x4 a00 = __builtin_amdgcn_mfma_f32_16x16x32_bf16(m0h, asbf(cur[0]), z, 0,0,0);\
        a00 = __builtin_amdgcn_mfma_f32_16x16x32_bf16(m0l, asbf(cur[0]), a00, 0,0,0);    \
        a00 = __builtin_amdgcn_mfma_f32_16x16x32_bf16(m0h, asbf(cur[1]), a00, 0,0,0);    \
        f32x4 a01 = __builtin_amdgcn_mfma_f32_16x16x32_bf16(m1h, asbf(cur[2]), z, 0,0,0);\
        a01 = __builtin_amdgcn_mfma_f32_16x16x32_bf16(m1l, asbf(cur[2]), a01, 0,0,0);    \
        a01 = __builtin_amdgcn_mfma_f32_16x16x32_bf16(m1h, asbf(cur[3]), a01, 0,0,0);    \
        f32x4 a10 = __builtin_amdgcn_mfma_f32_16x16x32_bf16(m0h, asbf(cur[4]), z, 0,0,0);\
        a10 = __builtin_amdgcn_mfma_f32_16x16x32_bf16(m0l, asbf(cur[4]), a10, 0,0,0);    \
        a10 = __builtin_amdgcn_mfma_f32_16x16x32_bf16(m0h, asbf(cur[5]), a10, 0,0,0);    \
        f32x4 a11 = __builtin_amdgcn_mfma_f32_16x16x32_bf16(m1h, asbf(cur[6]), z, 0,0,0);\
        a11 = __builtin_amdgcn_mfma_f32_16x16x32_bf16(m1l, asbf(cur[6]), a11, 0,0,0);    \
        a11 = __builtin_amdgcn_mfma_f32_16x16x32_bf16(m1h, asbf(cur[7]), a11, 0,0,0);    \
        f32x4 y0 = a00 + a01;                                                            \
        f32x4 y1 = a10 + a11;                                                            \
        _Pragma("unroll")                                                                \
        for (int reg = 0; reg < 4; ++reg) {                                              \
            Tw[(quad * 4 + reg) * 33 + r]      = y0[reg];                                \
            Tw[(quad * 4 + reg) * 33 + 16 + r] = y1[reg];                                \
        }                                                                                \
        float ss = 0.f;                                                                  \
        _Pragma("unroll")                                                                \
        for (int j = 0; j < 8; ++j) {                                                    \
            mm[j] = Tw[r * 33 + quad * 8 + j];                                           \
            ss = fmaf(mm[j], mm[j], ss);                                                 \
        }                                                                                \
        ss += __shfl_xor(ss, 16);                                                        \
        ss += __shfl_xor(ss, 32);                                                        \
        float kk = 1.0f / (sqrtf(ss) + EPS_NORM);                                        \
        _Pragma("unroll")                                                                \
        for (int j = 0; j < 8; ++j) mm[j] *= kk;                                         \
    }

#define READOUT_BODY(CN_, SN_, FLAGIDX)                                                  \
    {                                                                                    \
        const float* kn = ws + WS_CN;                                                    \
        float acc[10];                                                                   \
        _Pragma("unroll")                                                                \
        for (int c = 0; c < 10; ++c) acc[c] = 0.f;                                       \
        _Pragma("unroll")                                                                \
        for (int j = 0; j < 8; ++j) {                                                    \
            int a = quad * 8 + j;                                                        \
            float Ma = mm[j];                                                            \
            _Pragma("unroll")                                                            \
            for (int c = 0; c < 10; ++c) {                                               \
                float fin = (CN_) * kn[a * 10 + c] + (SN_) * kn[320 + a * 10 + c];       \
                acc[c] = fmaf(Ma, fin, acc[c]);                                          \
            }                                                                            \
        }                                                                                \
        _Pragma("unroll")                                                                \
        for (int c = 0; c < 10; ++c) {                                                   \
            acc[c] += __shfl_xor(acc[c], 16);                                            \
            acc[c] += __shfl_xor(acc[c], 32);                                            \
        }                                                                                \
        const unsigned bf = *(const unsigned*)(ws + (FLAGIDX));                          \
        if (quad == 0) {                                                                 \
            if (bf) {                                                                    \
                __hip_bfloat16* o = (__hip_bfloat16*)out;                                \
                _Pragma("unroll")                                                        \
                for (int c = 0; c < 10; ++c)                                             \
                    o[(size_t)(b0 + r) * 10 + c] = __float2bfloat16(acc[c]);             \
            } else {                                                                     \
                float* o = (float*)out;                                                  \
                _Pragma("unroll")                                                        \
                for (int c = 0; c < 10; ++c)                                             \
                    o[(size_t)(b0 + r) * 10 + c] = acc[c];                               \
            }                                                                            \
        }                                                                                \
    }

// ---------------- fallback main (round-11 verbatim behavior) ----------------
__global__ __launch_bounds__(256)
void mps_mfma(const float* __restrict__ ws, void* __restrict__ out) {
    __shared__ float T[4][528];
    const int lane = threadIdx.x & 63;
    const int w    = threadIdx.x >> 6;
    const int r    = lane & 15;
    const int quad = lane >> 4;
    const int b0   = (blockIdx.x * 4 + w) * 16;
    const float* __restrict__ xT = ws + WS_X;
    const uint4* __restrict__ BF = (const uint4*)ws;
    float* __restrict__ Tw = &T[w][0];

    float mm[8];
    {
        float x0 = xT[b0 + r];
        float sn, cs; __sincosf(HALF_PI_F * x0, &sn, &cs);
        const float* c0 = ws + WS_C0;
        #pragma unroll
        for (int j = 0; j < 8; ++j) {
            int a = quad * 8 + j;
            mm[j] = cs * c0[a] + sn * c0[32 + a];
        }
    }
    uint4 cur[8];
    {
        const uint4* Bt = BF + lane;
        #pragma unroll
        for (int q = 0; q < 8; ++q) cur[q] = Bt[q * 64];
    }
    float xc = xT[(size_t)B_TOTAL + b0 + r];

    #pragma unroll 1
    for (int t = 0; t < N_MID; ++t) {
        const int tn = (t + 1 < N_MID) ? (t + 1) : t;
        const uint4* Bn = BF + (size_t)(tn * 8) * 64 + lane;
        uint4 nxt[8];
        #pragma unroll
        for (int q = 0; q < 8; ++q) nxt[q] = Bn[q * 64];
        float xn = xT[(size_t)(2 + t) * B_TOTAL + b0 + r];

        float st, ct; __sincosf(HALF_PI_F * xc, &st, &ct);
        CHAIN_STEP_BODY(ct, st)

        xc = xn;
        #pragma unroll
        for (int q = 0; q < 8; ++q) cur[q] = nxt[q];
    }
    float sN, cN; __sincosf(HALF_PI_F * xc, &sN, &cN);
    READOUT_BODY(cN, sN, WS_FLAG)
}

// ---------------- SC main: prefetched (cos,sin) pairs, zero in-loop sincos ----------------
__global__ __launch_bounds__(256)
void mps_sc(const float* __restrict__ ws, void* __restrict__ out) {
    __shared__ float T[4][528];
    const int lane = threadIdx.x & 63;
    const int w    = threadIdx.x >> 6;
    const int r    = lane & 15;
    const int quad = lane >> 4;
    const int b0   = (blockIdx.x * 4 + w) * 16;
    const float2* __restrict__ SC = (const float2*)(ws + WS_SC);
    const uint4* __restrict__ BF = (const uint4*)ws;
    float* __restrict__ Tw = &T[w][0];

    float mm[8];
    {
        float2 p0 = SC[b0 + r];                 // site 0: (cos, sin)
        const float* c0 = ws + WS_C0;
        #pragma unroll
        for (int j = 0; j < 8; ++j) {
            int a = quad * 8 + j;
            mm[j] = p0.x * c0[a] + p0.y * c0[32 + a];
        }
    }
    uint4 cur[8];
    {
        const uint4* Bt = BF + lane;
        #pragma unroll
        for (int q = 0; q < 8; ++q) cur[q] = Bt[q * 64];
    }
    float2 scc = SC[(size_t)B_TOTAL + b0 + r];  // site 1 (t=0)

    #pragma unroll 1
    for (int t = 0; t < N_MID; ++t) {
        const int tn = (t + 1 < N_MID) ? (t + 1) : t;
        const uint4* Bn = BF + (size_t)(tn * 8) * 64 + lane;
        uint4 nxt[8];
        #pragma unroll
        for (int q = 0; q < 8; ++q) nxt[q] = Bn[q * 64];
        float2 scn = SC[(size_t)(2 + t) * B_TOTAL + b0 + r];

        CHAIN_STEP_BODY(scc.x, scc.y)

        scc = scn;
        #pragma unroll
        for (int q = 0; q < 8; ++q) cur[q] = nxt[q];
    }
    // scc now holds site-255 pair
    READOUT_BODY(scc.x, scc.y, WS_FLAG2)
}

// ---------------- launch ----------------
extern "C" void kernel_launch(void* const* d_in, const int* in_sizes, int n_in,
                              void* d_out, int out_size, void* d_ws, size_t ws_size,
                              hipStream_t stream) {
    float* ws = (float*)d_ws;
    if (ws_size >= WS_NEEDED_SC) {
        aux_sc<<<2557, 256, 0, stream>>>(d_in[0], d_in[1], d_in[2], d_in[3], ws);
        mps_sc<<<512, 256, 0, stream>>>(ws, d_out);
    } else {
        aux_all<<<2557, 256, 0, stream>>>(d_in[0], d_in[1], d_in[2], d_in[3], ws);
        mps_mfma<<<512, 256, 0, stream>>>(ws, d_out);
    }
}